// Round 3
// baseline (116.683 us; speedup 1.0000x reference)
//
#include <hip/hip_runtime.h>

#define D_DIM 1024
#define B_DIM 128
#define C_DIM 1000
#define M_ALL 1152   // 128 x-rows + 1000 mu-rows + 24 zero-pad rows
#define EPSF 1e-6f

typedef __attribute__((ext_vector_type(8))) short short8;   // 8 bf16 = 4 VGPRs
typedef __attribute__((ext_vector_type(4))) float f32x4;

static __device__ __forceinline__ unsigned short f2bf(float f) {
    union { float f; unsigned int u; } v; v.f = f;
    unsigned int u = v.u;
    u += 0x7fffu + ((u >> 16) & 1u);   // round-to-nearest-even
    return (unsigned short)(u >> 16);
}

// ---------------------------------------------------------------------------
// Dispatch 1: pack A (x;mu;pad) -> bf16 + per-row (eps*||a||^2, beta.a),
//             and pack LT[n][k] = tril(L)[k][n] -> bf16 (transposed, masked).
// Blocks [0, M_ALL): one row each. Blocks [M_ALL, M_ALL+256): one 64x64 L-tile.
// ---------------------------------------------------------------------------
__global__ __launch_bounds__(256)
void pack_all(const float* __restrict__ x, const float* __restrict__ mu,
              const float* __restrict__ beta, const float* __restrict__ L,
              unsigned short* __restrict__ A_bf, unsigned short* __restrict__ LT,
              float* __restrict__ nrm, float* __restrict__ bdot) {
    __shared__ unsigned short tile[64][65];
    __shared__ float red[2][4];
    const int tid = threadIdx.x;

    if (blockIdx.x < M_ALL) {
        const int m = blockIdx.x;
        float4 v;
        if (m < B_DIM)              v = *(const float4*)(x + m * D_DIM + tid * 4);
        else if (m < B_DIM + C_DIM) v = *(const float4*)(mu + (m - B_DIM) * D_DIM + tid * 4);
        else                        v = make_float4(0.f, 0.f, 0.f, 0.f);
        ushort4 o;
        o.x = f2bf(v.x); o.y = f2bf(v.y); o.z = f2bf(v.z); o.w = f2bf(v.w);
        *(ushort4*)(A_bf + m * D_DIM + tid * 4) = o;

        const float4 bt = *(const float4*)(beta + tid * 4);
        float sa = v.x*v.x + v.y*v.y + v.z*v.z + v.w*v.w;
        float sb = bt.x*v.x + bt.y*v.y + bt.z*v.z + bt.w*v.w;
#pragma unroll
        for (int off = 32; off > 0; off >>= 1) {
            sa += __shfl_down(sa, off);
            sb += __shfl_down(sb, off);
        }
        int lane = tid & 63, wid = tid >> 6;
        if (lane == 0) { red[0][wid] = sa; red[1][wid] = sb; }
        __syncthreads();
        if (tid == 0) {
            float a2 = red[0][0] + red[0][1] + red[0][2] + red[0][3];
            float b2 = red[1][0] + red[1][1] + red[1][2] + red[1][3];
            nrm[m]  = EPSF * a2;   // base; gemm_p atomically adds ||P_row||^2
            bdot[m] = b2;
        }
    } else {
        const int t = blockIdx.x - M_ALL;          // 0..255
        const int k0 = (t >> 4) * 64, n0 = (t & 15) * 64;
        const int tn = tid & 63, tq = tid >> 6;    // tq in 0..3
#pragma unroll
        for (int i = 0; i < 16; ++i) {
            int kk = tq + i * 4;
            int k = k0 + kk, n = n0 + tn;
            float v = (k >= n) ? L[k * D_DIM + n] : 0.f;   // coalesced in n
            tile[tn][kk] = f2bf(v);
        }
        __syncthreads();
#pragma unroll
        for (int i = 0; i < 16; ++i) {
            int nn = tq + i * 4;
            LT[(n0 + nn) * D_DIM + k0 + tn] = tile[nn][tn];  // coalesced in k
        }
    }
}

// ---------------------------------------------------------------------------
// Dispatch 2: P = A @ tril(L), bf16 MFMA, LDS-free / barrier-free.
// One wave per 32x32 output tile (1152 waves, 288 blocks). Triangular K-skip.
// Epilogue: bf16 P write + atomicAdd of per-row ||P||^2 partials into nrm.
// ---------------------------------------------------------------------------
__global__ __launch_bounds__(256)
void gemm_p(const unsigned short* __restrict__ A, const unsigned short* __restrict__ BT,
            unsigned short* __restrict__ P, float* __restrict__ nrm) {
    const int wid  = blockIdx.x * 4 + (threadIdx.x >> 6);   // 0..1151
    const int lane = threadIdx.x & 63;
    const int mt = wid >> 5, nt = wid & 31;                 // waves in a block share mt
    const int m0 = mt * 32, n0 = nt * 32;
    const int lrow = lane & 15, q = lane >> 4;

    const unsigned short* a0p = A  + (m0 + lrow)      * D_DIM + q * 8;
    const unsigned short* a1p = A  + (m0 + 16 + lrow) * D_DIM + q * 8;
    const unsigned short* b0p = BT + (n0 + lrow)      * D_DIM + q * 8;
    const unsigned short* b1p = BT + (n0 + 16 + lrow) * D_DIM + q * 8;

    f32x4 acc[2][2] = {};
#pragma unroll 2
    for (int k0 = n0; k0 < D_DIM; k0 += 32) {   // tri-skip: BT zero for k < n
        short8 a0 = *(const short8*)(a0p + k0);
        short8 a1 = *(const short8*)(a1p + k0);
        short8 b0 = *(const short8*)(b0p + k0);
        short8 b1 = *(const short8*)(b1p + k0);
        acc[0][0] = __builtin_amdgcn_mfma_f32_16x16x32_bf16(a0, b0, acc[0][0], 0, 0, 0);
        acc[0][1] = __builtin_amdgcn_mfma_f32_16x16x32_bf16(a0, b1, acc[0][1], 0, 0, 0);
        acc[1][0] = __builtin_amdgcn_mfma_f32_16x16x32_bf16(a1, b0, acc[1][0], 0, 0, 0);
        acc[1][1] = __builtin_amdgcn_mfma_f32_16x16x32_bf16(a1, b1, acc[1][1], 0, 0, 0);
    }

    // C/D layout: col = lane&15 (lrow), row = q*4 + r
#pragma unroll
    for (int mi = 0; mi < 2; ++mi) {
#pragma unroll
        for (int r = 0; r < 4; ++r) {
            int m = m0 + mi * 16 + q * 4 + r;
            float p0 = acc[mi][0][r], p1 = acc[mi][1][r];
            P[m * D_DIM + n0 + lrow]      = f2bf(p0);
            P[m * D_DIM + n0 + 16 + lrow] = f2bf(p1);
            float s = p0 * p0 + p1 * p1;            // this lane's 2 cols
#pragma unroll
            for (int off = 1; off < 16; off <<= 1)  // reduce over 16 lrow lanes
                s += __shfl_xor(s, off);
            if (lrow == 0) atomicAdd(&nrm[m], s);
        }
    }
}

// ---------------------------------------------------------------------------
// Dispatch 3: fused cross-GEMM + epilogue. One wave per 16x16 out tile,
// LDS-free / barrier-free. 8 b-tiles x 63 c-tiles = 504 waves = 126 blocks.
// out[b,c] = -scale*( sqrt(nrm[b]+nrm[128+c]-2*u_b.v_c+eps)
//                     + lmbda*sqrt((bdot[b]-bdot[128+c])^2+eps) )
// ---------------------------------------------------------------------------
__global__ __launch_bounds__(256)
void gemm_cross(const unsigned short* __restrict__ UV,
                const float* __restrict__ nrm, const float* __restrict__ bdot,
                const float* __restrict__ lmbda_p, const float* __restrict__ scale_p,
                float* __restrict__ out) {
    const int wid  = blockIdx.x * 4 + (threadIdx.x >> 6);   // 0..503
    const int lane = threadIdx.x & 63;
    const int bt = wid / 63, ct = wid % 63;
    const int b0 = bt * 16, c0 = ct * 16;
    const int lrow = lane & 15, q = lane >> 4;

    const unsigned short* up = UV + (b0 + lrow) * D_DIM + q * 8;                 // u rows
    const unsigned short* vp = UV + (B_DIM + c0 + lrow) * D_DIM + q * 8;         // v rows

    f32x4 acc = {};
#pragma unroll 4
    for (int k0 = 0; k0 < D_DIM; k0 += 32) {
        short8 a = *(const short8*)(up + k0);
        short8 b = *(const short8*)(vp + k0);
        acc = __builtin_amdgcn_mfma_f32_16x16x32_bf16(a, b, acc, 0, 0, 0);
    }

    const float lm = *lmbda_p, sc = *scale_p;
    const int c = c0 + lrow;
    if (c < C_DIM) {
        float nm = nrm[B_DIM + c], bm = bdot[B_DIM + c];
#pragma unroll
        for (int r = 0; r < 4; ++r) {
            int b = b0 + q * 4 + r;
            float quad = nrm[b] + nm - 2.f * acc[r] + EPSF;
            quad = fmaxf(quad, 0.f);
            float bd = bdot[b] - bm;
            out[b * C_DIM + c] = -sc * (sqrtf(quad) + lm * sqrtf(fmaf(bd, bd, EPSF)));
        }
    }
}

extern "C" void kernel_launch(void* const* d_in, const int* in_sizes, int n_in,
                              void* d_out, int out_size, void* d_ws, size_t ws_size,
                              hipStream_t stream) {
    const float* x     = (const float*)d_in[0];   // [128,1024]
    const float* mu    = (const float*)d_in[1];   // [1000,1024]
    const float* beta  = (const float*)d_in[2];   // [1024]
    const float* L     = (const float*)d_in[3];   // [1024,1024]
    const float* lmbda = (const float*)d_in[4];
    const float* scale = (const float*)d_in[5];
    float* out = (float*)d_out;                   // [128,1000]

    char* ws = (char*)d_ws;
    unsigned short* A_bf  = (unsigned short*)ws;                       // 1152*1024*2
    unsigned short* LT_bf = (unsigned short*)(ws + 2359296);           // 1024*1024*2
    unsigned short* uv_bf = (unsigned short*)(ws + 2359296 + 2097152); // 1152*1024*2
    float* fws  = (float*)(ws + 2359296 + 2097152 + 2359296);
    float* nrm  = fws;            // [1152]: eps*||a||^2 + ||P_row||^2
    float* bdot = fws + M_ALL;    // [1152]: beta . a

    dim3 blk(256);
    pack_all  <<<M_ALL + 256, blk, 0, stream>>>(x, mu, beta, L, A_bf, LT_bf, nrm, bdot);
    gemm_p    <<<288, blk, 0, stream>>>(A_bf, LT_bf, uv_bf, nrm);
    gemm_cross<<<126, blk, 0, stream>>>(uv_bf, nrm, bdot, lmbda, scale, out);
}